// Round 22
// baseline (96.559 us; speedup 1.0000x reference)
//
#include <hip/hip_runtime.h>
#include <math.h>
#include <cstddef>

// AttentionBlock: B=4, L=2048, C=512, H=8, Dk=64
// qkv = x @ W_in + b_in ; per head: causal-softmax(q k^T/8) @ v ; @ W_out + b_out + x

constexpr int B_SZ  = 4;
constexpr int L_SEQ = 2048;
constexpr int C_DIM = 512;
constexpr int H_N   = 8;
constexpr int DK    = 64;
constexpr int N_QKV = 1536;
constexpr int M_ROWS = B_SZ * L_SEQ; // 8192
constexpr float SCALE = 0.125f;
constexpr float DEFER_THR = 8.f;     // defer-max threshold (P <= e^8)

typedef __attribute__((ext_vector_type(4))) float f32x4;
typedef __attribute__((ext_vector_type(8))) short bf16x8;

static __device__ inline ushort f2bf(float f) {
  unsigned u = __builtin_bit_cast(unsigned, f);
  u += 0x7fffu + ((u >> 16) & 1u);
  return (ushort)(u >> 16);
}

typedef __attribute__((address_space(1))) const unsigned int* gas1_t;
typedef __attribute__((address_space(3))) unsigned int* las3_t;
static __device__ inline void gload_lds16(const void* g, void* l) {
  __builtin_amdgcn_global_load_lds((gas1_t)g, (las3_t)l, 16, 0, 0);
}

// K/V tile format (producer-swizzled so LDS-linear staging => conflict-
// balanced ds_read_b128): per (bh, 64-j tile) an 8KB tile of [64 rows][8
// chunks of 16B]; chunk stored at (logical_chunk ^ (row & 7)). K tiles:
// row = j, elem d. V tiles: row = d, elem j.

// ------------------------------------------------- fused prep (1 launch)
__global__ __launch_bounds__(256) void prep_fused(
    const float* __restrict__ x, const float* __restrict__ W_in,
    const float* __restrict__ W_out, ushort* __restrict__ xbf,
    ushort* __restrict__ WinT, ushort* __restrict__ WoutT) {
  const int id = blockIdx.x;
  if (id < 4096) {
    const int i = id * 256 + threadIdx.x;
    const float4 v = reinterpret_cast<const float4*>(x)[i];
    ushort4 o;
    o.x = f2bf(v.x); o.y = f2bf(v.y); o.z = f2bf(v.z); o.w = f2bf(v.w);
    reinterpret_cast<ushort4*>(xbf)[i] = o;
    return;
  }
  __shared__ ushort T[64][65];
  const float* src;
  ushort* dst;
  int R, C, c0, r0;
  if (id < 4096 + 192) {
    const int t = id - 4096;
    src = W_in; dst = WinT; R = C_DIM; C = N_QKV;
    c0 = (t % 24) * 64; r0 = (t / 24) * 64;
  } else {
    const int t = id - 4288;
    src = W_out; dst = WoutT; R = C_DIM; C = C_DIM;
    c0 = (t % 8) * 64; r0 = (t / 8) * 64;
  }
#pragma unroll
  for (int p = 0; p < 16; ++p) {
    const int idx = threadIdx.x + p * 256;
    const int r = idx >> 6, c = idx & 63;
    T[r][c] = f2bf(src[(size_t)(r0 + r) * C + c0 + c]);
  }
  __syncthreads();
#pragma unroll
  for (int p = 0; p < 16; ++p) {
    const int idx = threadIdx.x + p * 256;
    const int r = idx >> 6, c = idx & 63;
    dst[(size_t)(c0 + r) * R + r0 + c] = T[c][r];
  }
}

// ----------------------------------------- bf16 MFMA GEMM 64x128, BK=32
// TLP-oriented tile: grid doubles vs 128x128 (GEMM1 1536 blocks = 6/CU,
// GEMM2 512 = 2/CU) so staging latency overlaps across blocks; acc halves
// (2x4 frags) -> fewer VGPR, more resident waves. XCD banding (T1):
// xcd=id&7 owns a contiguous 16-strip (64-row) M-band x all nbx N-strips.
// FIX vs R21: full staging — B = 512 chunks (2 rounds x all waves),
// A = 256 chunks (1 round x all waves); R21 issued half => NaN.
template <int EPI>
__global__ __launch_bounds__(256) void gemm_bf16(
    const ushort* __restrict__ A, const ushort* __restrict__ Bt,
    const float* __restrict__ bias, ushort* __restrict__ Qo,
    ushort* __restrict__ Ko, ushort* __restrict__ Vto,
    float* __restrict__ outF, const float* __restrict__ resid,
    int N, int K, int nbx) {
  __shared__ ushort Al[64 * 32];
  __shared__ ushort Bl[128 * 32];
  const int id = blockIdx.x;
  const int xcd = id & 7, i = id >> 3;
  const int bn = (i % nbx) * 128;
  const int bm = (xcd * 16 + i / nbx) * 64;   // 16 M-strips (64 rows) per XCD
  const int tid = threadIdx.x;
  const int w = tid >> 6, l = tid & 63;
  const int cc = l & 15, gg = l >> 4;
  const int wr = w >> 1, wc = w & 1;          // wave: rows wr*32+, cols wc*64+
  f32x4 acc[2][4] = {};

  for (int k0 = 0; k0 < K; k0 += 32) {
    // B tile: 128x32 bf16 = 512 16B-chunks (2 rounds, all 4 waves)
#pragma unroll
    for (int q = 0; q < 2; ++q) {
      const int cbase = q * 256 + w * 64;
      const int c = cbase + l;
      gload_lds16(Bt + (size_t)(bn + (c >> 2)) * K + k0 + (c & 3) * 8,
                  &Bl[cbase * 8]);
    }
    // A tile: 64x32 bf16 = 256 16B-chunks (1 round, all 4 waves)
    {
      const int cbase = w * 64;
      const int c = cbase + l;
      gload_lds16(A + (size_t)(bm + (c >> 2)) * K + k0 + (c & 3) * 8,
                  &Al[cbase * 8]);
    }
    __syncthreads();
    bf16x8 aF[2], bF[4];
#pragma unroll
    for (int i2 = 0; i2 < 2; ++i2)
      aF[i2] = *reinterpret_cast<const bf16x8*>(
          &Al[(wr * 32 + i2 * 16 + cc) * 32 + gg * 8]);
#pragma unroll
    for (int j = 0; j < 4; ++j)
      bF[j] = *reinterpret_cast<const bf16x8*>(
          &Bl[(wc * 64 + j * 16 + cc) * 32 + gg * 8]);
#pragma unroll
    for (int i2 = 0; i2 < 2; ++i2)
#pragma unroll
      for (int j = 0; j < 4; ++j)
        acc[i2][j] = __builtin_amdgcn_mfma_f32_16x16x32_bf16(aF[i2], bF[j],
                                                             acc[i2][j], 0, 0, 0);
    __syncthreads();
  }

  if (EPI == 0) {
#pragma unroll
    for (int j = 0; j < 4; ++j) {
      const int colbase = bn + wc * 64 + j * 16;
      const int h = colbase / 192, rem = colbase % 192;
      const int type = rem / 64, d = (rem % 64) + cc;
      const float bv = bias[colbase + cc];
#pragma unroll
      for (int i2 = 0; i2 < 2; ++i2) {
        const int rowbase = bm + wr * 32 + i2 * 16 + 4 * gg;
        const int b = rowbase >> 11, ll = rowbase & 2047;
        const size_t bh32 = (size_t)(b * H_N + h) * 32;
        if (type == 0) {
#pragma unroll
          for (int r = 0; r < 4; ++r)
            Qo[((size_t)(b * H_N + h) * L_SEQ + ll + r) * DK + d] =
                f2bf(acc[i2][j][r] + bv);
        } else if (type == 1) {
#pragma unroll
          for (int r = 0; r < 4; ++r) {
            const int jg = ll + r;
            Ko[(bh32 + (jg >> 6)) * 4096 + (jg & 63) * 64 +
               (((d >> 3) ^ (jg & 7)) << 3) + (d & 7)] =
                f2bf(acc[i2][j][r] + bv);
          }
        } else {
          ushort4 pk;
          pk.x = f2bf(acc[i2][j][0] + bv);
          pk.y = f2bf(acc[i2][j][1] + bv);
          pk.z = f2bf(acc[i2][j][2] + bv);
          pk.w = f2bf(acc[i2][j][3] + bv);
          const size_t idx = (bh32 + (ll >> 6)) * 4096 + (size_t)d * 64 +
                             ((((ll & 63) >> 3) ^ (d & 7)) << 3) + (ll & 7);
          *reinterpret_cast<ushort4*>(&Vto[idx]) = pk;
        }
      }
    }
  } else {
#pragma unroll
    for (int j = 0; j < 4; ++j) {
      const int col = bn + wc * 64 + j * 16 + cc;
      const float bv = bias[col];
#pragma unroll
      for (int i2 = 0; i2 < 2; ++i2) {
        const int rowbase = bm + wr * 32 + i2 * 16 + 4 * gg;
#pragma unroll
        for (int r = 0; r < 4; ++r) {
          const size_t off = (size_t)(rowbase + r) * N + col;
          outF[off] = acc[i2][j][r] + bv + resid[off];
        }
      }
    }
  }
}

// ---------------------------------------------- attention core (bf16 MFMA)
// EXACT R7/R15/R19 kernel (best measured: 48.7-49.1us).
#define STAGE(buf, tile)                                                     \
  {                                                                          \
    const ushort* kg_ = KoB + (size_t)(tile) * 4096 + w * 1024 + lane * 8;   \
    const ushort* vg_ = VtB + (size_t)(tile) * 4096 + w * 1024 + lane * 8;   \
    gload_lds16(kg_, &Ks[buf][w * 1024]);                                    \
    gload_lds16(kg_ + 512, &Ks[buf][w * 1024 + 512]);                        \
    gload_lds16(vg_, &Vs[buf][w * 1024]);                                    \
    gload_lds16(vg_ + 512, &Vs[buf][w * 1024 + 512]);                        \
  }

__global__ __launch_bounds__(256, 4) void attn_mfma(
    const ushort* __restrict__ Q, const ushort* __restrict__ Ko,
    const ushort* __restrict__ Vt, ushort* __restrict__ attn_out) {
  __shared__ ushort Ks[2][4096];
  __shared__ ushort Vs[2][4096];
  __shared__ ushort Pw_s[4][1024];
  const int id = blockIdx.x;
  const int bh = (id & 7) + 8 * ((id >> 3) & 3);
  const int qt = 31 - (id >> 5);
  const int tid = threadIdx.x;
  const int w = tid >> 6, lane = tid & 63;
  const int c = lane & 15, g = lane >> 4;
  const int b = bh >> 3, h = bh & 7;
  const ushort* KoB = Ko + (size_t)bh * 32 * 4096;
  const ushort* VtB = Vt + (size_t)bh * 32 * 4096;
  const int q0 = qt * 64 + w * 16;
  ushort* Pw = Pw_s[w];
  const int pc0 = (g ^ (c & 7)) * 8;
  const int pc1 = ((g + 4) ^ (c & 7)) * 8;

  bf16x8 qA[2];
  {
    const ushort* qp = Q + ((size_t)bh * L_SEQ + q0 + c) * DK + g * 8;
    qA[0] = *reinterpret_cast<const bf16x8*>(qp);
    qA[1] = *reinterpret_cast<const bf16x8*>(qp + 32);
  }

  f32x4 O[4] = {};
  float mrow[4] = {-INFINITY, -INFINITY, -INFINITY, -INFINITY};
  float lsum[4] = {};
  const f32x4 zero4 = {0.f, 0.f, 0.f, 0.f};

  STAGE(0, 0);
  __syncthreads();

  for (int jt = 0; jt <= qt; ++jt) {
    const int cur = jt & 1;
    if (jt < qt) STAGE(cur ^ 1, jt + 1);
    const ushort* Kc = Ks[cur];
    const ushort* Vc = Vs[cur];
    const int j0 = jt * 64;
    f32x4 S[4];
#pragma unroll
    for (int n = 0; n < 4; ++n) {
      const bf16x8 k0 = *reinterpret_cast<const bf16x8*>(&Kc[(n * 16 + c) * 64 + pc0]);
      const bf16x8 k1 = *reinterpret_cast<const bf16x8*>(&Kc[(n * 16 + c) * 64 + pc1]);
      S[n] = __builtin_amdgcn_mfma_f32_16x16x32_bf16(qA[0], k0, zero4, 0, 0, 0);
      S[n] = __builtin_amdgcn_mfma_f32_16x16x32_bf16(qA[1], k1, S[n], 0, 0, 0);
    }
    const bool diag = (jt == qt);
#pragma unroll
    for (int n = 0; n < 4; ++n)
#pragma unroll
      for (int r = 0; r < 4; ++r) {
        float v = S[n][r] * SCALE;
        if (diag && (j0 + n * 16 + c) > (q0 + 4 * g + r)) v = -INFINITY;
        S[n][r] = v;
      }
    float pm[4];
    int exceed = 0;
#pragma unroll
    for (int r = 0; r < 4; ++r) {
      pm[r] = fmaxf(fmaxf(S[0][r], S[1][r]), fmaxf(S[2][r], S[3][r]));
      exceed |= (pm[r] > mrow[r] + DEFER_THR);
    }
    if (__any(exceed)) {
#pragma unroll
      for (int r = 0; r < 4; ++r) {
        float fm = pm[r];
        fm = fmaxf(fm, __shfl_xor(fm, 1, 16));
        fm = fmaxf(fm, __shfl_xor(fm, 2, 16));
        fm = fmaxf(fm, __shfl_xor(fm, 4, 16));
        fm = fmaxf(fm, __shfl_xor(fm, 8, 16));
        const float mnew = fmaxf(mrow[r], fm);
        const float corr = __expf(mrow[r] - mnew);
        lsum[r] *= corr;
#pragma unroll
        for (int t = 0; t < 4; ++t) O[t][r] *= corr;
        mrow[r] = mnew;
      }
    }
#pragma unroll
    for (int n = 0; n < 4; ++n)
#pragma unroll
      for (int r = 0; r < 4; ++r) {
        const float p = __expf(S[n][r] - mrow[r]);
        S[n][r] = p;
        lsum[r] += p;
      }
#pragma unroll
    for (int n = 0; n < 4; ++n)
#pragma unroll
      for (int r = 0; r < 4; ++r) {
        const int row = 4 * g + r;
        Pw[row * 64 + ((2 * n + (c >> 3)) ^ (row & 7)) * 8 + (c & 7)] =
            f2bf(S[n][r]);
      }
    const bf16x8 pA0 = *reinterpret_cast<const bf16x8*>(&Pw[c * 64 + pc0]);
    const bf16x8 pA1 = *reinterpret_cast<const bf16x8*>(&Pw[c * 64 + pc1]);
#pragma unroll
    for (int t = 0; t < 4; ++t) {
      const bf16x8 v0 = *reinterpret_cast<const bf16x8*>(&Vc[(t * 16 + c) * 64 + pc0]);
      const bf16x8 v1 = *reinterpret_cast<const bf16x8*>(&Vc[(t * 16 + c) * 64 + pc1]);
      O[t] = __builtin_amdgcn_mfma_f32_16x16x32_bf16(pA0, v0, O[t], 0, 0, 0);
      O[t] = __builtin_amdgcn_mfma_f32_16x16x32_bf16(pA1, v1, O[t], 0, 0, 0);
    }
    __syncthreads();
  }
  float inv[4];
#pragma unroll
  for (int r = 0; r < 4; ++r) {
    float s = lsum[r];
    s += __shfl_xor(s, 1, 16);
    s += __shfl_xor(s, 2, 16);
    s += __shfl_xor(s, 4, 16);
    s += __shfl_xor(s, 8, 16);
    inv[r] = 1.f / s;
  }
#pragma unroll
  for (int t = 0; t < 4; ++t)
#pragma unroll
    for (int r = 0; r < 4; ++r)
      attn_out[((size_t)b * L_SEQ + q0 + 4 * g + r) * C_DIM + h * DK + t * 16 + c] =
          f2bf(O[t][r] * inv[r]);
}

// ------------------------------------------------------------------- launch
extern "C" void kernel_launch(void* const* d_in, const int* in_sizes, int n_in,
                              void* d_out, int out_size, void* d_ws,
                              size_t ws_size, hipStream_t stream) {
  const float* x     = (const float*)d_in[0];
  const float* W_in  = (const float*)d_in[1];
  const float* b_in  = (const float*)d_in[2];
  const float* W_out = (const float*)d_in[3];
  const float* b_out = (const float*)d_in[4];
  float* out = (float*)d_out;

  ushort* xbf   = (ushort*)d_ws;                       // 8192x512
  ushort* WinT  = xbf + (size_t)M_ROWS * C_DIM;        // 1536x512
  ushort* WoutT = WinT + (size_t)N_QKV * C_DIM;        // 512x512
  ushort* Qo    = WoutT + (size_t)C_DIM * C_DIM;       // [BH,L,64]
  ushort* Ko    = Qo + (size_t)M_ROWS * C_DIM;         // [BH,32 tiles,4096]
  ushort* Vto   = Ko + (size_t)M_ROWS * C_DIM;         // [BH,32 tiles,4096]
  ushort* attnb = Vto + (size_t)M_ROWS * C_DIM;        // [8192,512]

  prep_fused<<<dim3(4352, 1, 1), 256, 0, stream>>>(
      x, W_in, W_out, xbf, WinT, WoutT);
  gemm_bf16<0><<<dim3(1536, 1, 1), 256, 0, stream>>>(
      xbf, WinT, b_in, Qo, Ko, Vto, nullptr, nullptr, N_QKV, C_DIM, 12);
  attn_mfma<<<dim3(1024, 1, 1), 256, 0, stream>>>(Qo, Ko, Vto, attnb);
  gemm_bf16<1><<<dim3(512, 1, 1), 256, 0, stream>>>(
      attnb, WoutT, b_out, nullptr, nullptr, nullptr, out, x, C_DIM, C_DIM, 4);
}

// Round 23
// 90.444 us; speedup vs baseline: 1.0676x; 1.0676x over previous
//
#include <hip/hip_runtime.h>
#include <math.h>
#include <cstddef>

// AttentionBlock: B=4, L=2048, C=512, H=8, Dk=64
// qkv = x @ W_in + b_in ; per head: causal-softmax(q k^T/8) @ v ; @ W_out + b_out + x

constexpr int B_SZ  = 4;
constexpr int L_SEQ = 2048;
constexpr int C_DIM = 512;
constexpr int H_N   = 8;
constexpr int DK    = 64;
constexpr int N_QKV = 1536;
constexpr int M_ROWS = B_SZ * L_SEQ; // 8192
constexpr float SCALE = 0.125f;
constexpr float DEFER_THR = 8.f;     // defer-max threshold (P <= e^8)

typedef __attribute__((ext_vector_type(4))) float f32x4;
typedef __attribute__((ext_vector_type(8))) short bf16x8;

static __device__ inline ushort f2bf(float f) {
  unsigned u = __builtin_bit_cast(unsigned, f);
  u += 0x7fffu + ((u >> 16) & 1u);
  return (ushort)(u >> 16);
}

typedef __attribute__((address_space(1))) const unsigned int* gas1_t;
typedef __attribute__((address_space(3))) unsigned int* las3_t;
static __device__ inline void gload_lds16(const void* g, void* l) {
  __builtin_amdgcn_global_load_lds((gas1_t)g, (las3_t)l, 16, 0, 0);
}

// K/V tile format (producer-swizzled so LDS-linear staging => conflict-
// balanced ds_read_b128): per (bh, 64-j tile) an 8KB tile of [64 rows][8
// chunks of 16B]; chunk stored at (logical_chunk ^ (row & 7)). K tiles:
// row = j, elem d. V tiles: row = d, elem j.

// ------------------------------------------------- fused prep (1 launch)
__global__ __launch_bounds__(256) void prep_fused(
    const float* __restrict__ x, const float* __restrict__ W_in,
    const float* __restrict__ W_out, ushort* __restrict__ xbf,
    ushort* __restrict__ WinT, ushort* __restrict__ WoutT) {
  const int id = blockIdx.x;
  if (id < 4096) {
    const int i = id * 256 + threadIdx.x;
    const float4 v = reinterpret_cast<const float4*>(x)[i];
    ushort4 o;
    o.x = f2bf(v.x); o.y = f2bf(v.y); o.z = f2bf(v.z); o.w = f2bf(v.w);
    reinterpret_cast<ushort4*>(xbf)[i] = o;
    return;
  }
  __shared__ ushort T[64][65];
  const float* src;
  ushort* dst;
  int R, C, c0, r0;
  if (id < 4096 + 192) {
    const int t = id - 4096;
    src = W_in; dst = WinT; R = C_DIM; C = N_QKV;
    c0 = (t % 24) * 64; r0 = (t / 24) * 64;
  } else {
    const int t = id - 4288;
    src = W_out; dst = WoutT; R = C_DIM; C = C_DIM;
    c0 = (t % 8) * 64; r0 = (t / 8) * 64;
  }
#pragma unroll
  for (int p = 0; p < 16; ++p) {
    const int idx = threadIdx.x + p * 256;
    const int r = idx >> 6, c = idx & 63;
    T[r][c] = f2bf(src[(size_t)(r0 + r) * C + c0 + c]);
  }
  __syncthreads();
#pragma unroll
  for (int p = 0; p < 16; ++p) {
    const int idx = threadIdx.x + p * 256;
    const int r = idx >> 6, c = idx & 63;
    dst[(size_t)(c0 + r) * R + r0 + c] = T[c][r];
  }
}

// ------------------------------------- GEMM1: 128x128, BK=32, XCD-banded
// (R19 exact — measured best for the qkv GEMM: 3 blocks/CU, banded A/B
// L2-resident per XCD.)
__global__ __launch_bounds__(256) void gemm_qkv(
    const ushort* __restrict__ A, const ushort* __restrict__ Bt,
    const float* __restrict__ bias, ushort* __restrict__ Qo,
    ushort* __restrict__ Ko, ushort* __restrict__ Vto, int N, int K, int nbx) {
  __shared__ ushort Al[128 * 32];
  __shared__ ushort Bl[128 * 32];
  const int id = blockIdx.x;
  const int xcd = id & 7, i = id >> 3;
  const int bn = (i % nbx) * 128;
  const int bm = (xcd * 8 + i / nbx) * 128;
  const int tid = threadIdx.x;
  const int w = tid >> 6, l = tid & 63;
  const int cc = l & 15, gg = l >> 4;
  const int wr = w >> 1, wc = w & 1;
  f32x4 acc[4][4] = {};

  for (int k0 = 0; k0 < K; k0 += 32) {
#pragma unroll
    for (int q = 0; q < 2; ++q) {
      const int cbase = q * 256 + w * 64;
      const int c = cbase + l;
      gload_lds16(A + (size_t)(bm + (c >> 2)) * K + k0 + (c & 3) * 8,
                  &Al[cbase * 8]);
      gload_lds16(Bt + (size_t)(bn + (c >> 2)) * K + k0 + (c & 3) * 8,
                  &Bl[cbase * 8]);
    }
    __syncthreads();
    bf16x8 aF[4], bF[4];
#pragma unroll
    for (int i2 = 0; i2 < 4; ++i2)
      aF[i2] = *reinterpret_cast<const bf16x8*>(
          &Al[(wr * 64 + i2 * 16 + cc) * 32 + gg * 8]);
#pragma unroll
    for (int j = 0; j < 4; ++j)
      bF[j] = *reinterpret_cast<const bf16x8*>(
          &Bl[(wc * 64 + j * 16 + cc) * 32 + gg * 8]);
#pragma unroll
    for (int i2 = 0; i2 < 4; ++i2)
#pragma unroll
      for (int j = 0; j < 4; ++j)
        acc[i2][j] = __builtin_amdgcn_mfma_f32_16x16x32_bf16(aF[i2], bF[j],
                                                             acc[i2][j], 0, 0, 0);
    __syncthreads();
  }

#pragma unroll
  for (int j = 0; j < 4; ++j) {
    const int colbase = bn + wc * 64 + j * 16;
    const int h = colbase / 192, rem = colbase % 192;
    const int type = rem / 64, d = (rem % 64) + cc;
    const float bv = bias[colbase + cc];
#pragma unroll
    for (int i2 = 0; i2 < 4; ++i2) {
      const int rowbase = bm + wr * 64 + i2 * 16 + 4 * gg;
      const int b = rowbase >> 11, ll = rowbase & 2047;
      const size_t bh32 = (size_t)(b * H_N + h) * 32;
      if (type == 0) {
#pragma unroll
        for (int r = 0; r < 4; ++r)
          Qo[((size_t)(b * H_N + h) * L_SEQ + ll + r) * DK + d] =
              f2bf(acc[i2][j][r] + bv);
      } else if (type == 1) {
#pragma unroll
        for (int r = 0; r < 4; ++r) {
          const int jg = ll + r;
          Ko[(bh32 + (jg >> 6)) * 4096 + (jg & 63) * 64 +
             (((d >> 3) ^ (jg & 7)) << 3) + (d & 7)] =
              f2bf(acc[i2][j][r] + bv);
        }
      } else {
        ushort4 pk;
        pk.x = f2bf(acc[i2][j][0] + bv);
        pk.y = f2bf(acc[i2][j][1] + bv);
        pk.z = f2bf(acc[i2][j][2] + bv);
        pk.w = f2bf(acc[i2][j][3] + bv);
        const size_t idx = (bh32 + (ll >> 6)) * 4096 + (size_t)d * 64 +
                           ((((ll & 63) >> 3) ^ (d & 7)) << 3) + (ll & 7);
        *reinterpret_cast<ushort4*>(&Vto[idx]) = pk;
      }
    }
  }
}

// ------------------------------------- GEMM2: 64x128, BK=32, XCD-banded
// (R22 variant — 512 blocks = 2 blocks/CU vs 1 for 128x128; GEMM2 was the
// only kernel at 1/CU with zero latency-hiding.)
__global__ __launch_bounds__(256) void gemm_out(
    const ushort* __restrict__ A, const ushort* __restrict__ Bt,
    const float* __restrict__ bias, float* __restrict__ outF,
    const float* __restrict__ resid, int N, int K, int nbx) {
  __shared__ ushort Al[64 * 32];
  __shared__ ushort Bl[128 * 32];
  const int id = blockIdx.x;
  const int xcd = id & 7, i = id >> 3;
  const int bn = (i % nbx) * 128;
  const int bm = (xcd * 16 + i / nbx) * 64;
  const int tid = threadIdx.x;
  const int w = tid >> 6, l = tid & 63;
  const int cc = l & 15, gg = l >> 4;
  const int wr = w >> 1, wc = w & 1;
  f32x4 acc[2][4] = {};

  for (int k0 = 0; k0 < K; k0 += 32) {
#pragma unroll
    for (int q = 0; q < 2; ++q) {
      const int cbase = q * 256 + w * 64;
      const int c = cbase + l;
      gload_lds16(Bt + (size_t)(bn + (c >> 2)) * K + k0 + (c & 3) * 8,
                  &Bl[cbase * 8]);
    }
    {
      const int cbase = w * 64;
      const int c = cbase + l;
      gload_lds16(A + (size_t)(bm + (c >> 2)) * K + k0 + (c & 3) * 8,
                  &Al[cbase * 8]);
    }
    __syncthreads();
    bf16x8 aF[2], bF[4];
#pragma unroll
    for (int i2 = 0; i2 < 2; ++i2)
      aF[i2] = *reinterpret_cast<const bf16x8*>(
          &Al[(wr * 32 + i2 * 16 + cc) * 32 + gg * 8]);
#pragma unroll
    for (int j = 0; j < 4; ++j)
      bF[j] = *reinterpret_cast<const bf16x8*>(
          &Bl[(wc * 64 + j * 16 + cc) * 32 + gg * 8]);
#pragma unroll
    for (int i2 = 0; i2 < 2; ++i2)
#pragma unroll
      for (int j = 0; j < 4; ++j)
        acc[i2][j] = __builtin_amdgcn_mfma_f32_16x16x32_bf16(aF[i2], bF[j],
                                                             acc[i2][j], 0, 0, 0);
    __syncthreads();
  }

#pragma unroll
  for (int j = 0; j < 4; ++j) {
    const int col = bn + wc * 64 + j * 16 + cc;
    const float bv = bias[col];
#pragma unroll
    for (int i2 = 0; i2 < 2; ++i2) {
      const int rowbase = bm + wr * 32 + i2 * 16 + 4 * gg;
#pragma unroll
      for (int r = 0; r < 4; ++r) {
        const size_t off = (size_t)(rowbase + r) * N + col;
        outF[off] = acc[i2][j][r] + bv + resid[off];
      }
    }
  }
}

// ---------------------------------------------- attention core (bf16 MFMA)
// EXACT R7/R15/R19 kernel (best measured: 48.7-49.1us).
#define STAGE(buf, tile)                                                     \
  {                                                                          \
    const ushort* kg_ = KoB + (size_t)(tile) * 4096 + w * 1024 + lane * 8;   \
    const ushort* vg_ = VtB + (size_t)(tile) * 4096 + w * 1024 + lane * 8;   \
    gload_lds16(kg_, &Ks[buf][w * 1024]);                                    \
    gload_lds16(kg_ + 512, &Ks[buf][w * 1024 + 512]);                        \
    gload_lds16(vg_, &Vs[buf][w * 1024]);                                    \
    gload_lds16(vg_ + 512, &Vs[buf][w * 1024 + 512]);                        \
  }

__global__ __launch_bounds__(256, 4) void attn_mfma(
    const ushort* __restrict__ Q, const ushort* __restrict__ Ko,
    const ushort* __restrict__ Vt, ushort* __restrict__ attn_out) {
  __shared__ ushort Ks[2][4096];
  __shared__ ushort Vs[2][4096];
  __shared__ ushort Pw_s[4][1024];
  const int id = blockIdx.x;
  const int bh = (id & 7) + 8 * ((id >> 3) & 3);
  const int qt = 31 - (id >> 5);
  const int tid = threadIdx.x;
  const int w = tid >> 6, lane = tid & 63;
  const int c = lane & 15, g = lane >> 4;
  const int b = bh >> 3, h = bh & 7;
  const ushort* KoB = Ko + (size_t)bh * 32 * 4096;
  const ushort* VtB = Vt + (size_t)bh * 32 * 4096;
  const int q0 = qt * 64 + w * 16;
  ushort* Pw = Pw_s[w];
  const int pc0 = (g ^ (c & 7)) * 8;
  const int pc1 = ((g + 4) ^ (c & 7)) * 8;

  bf16x8 qA[2];
  {
    const ushort* qp = Q + ((size_t)bh * L_SEQ + q0 + c) * DK + g * 8;
    qA[0] = *reinterpret_cast<const bf16x8*>(qp);
    qA[1] = *reinterpret_cast<const bf16x8*>(qp + 32);
  }

  f32x4 O[4] = {};
  float mrow[4] = {-INFINITY, -INFINITY, -INFINITY, -INFINITY};
  float lsum[4] = {};
  const f32x4 zero4 = {0.f, 0.f, 0.f, 0.f};

  STAGE(0, 0);
  __syncthreads();

  for (int jt = 0; jt <= qt; ++jt) {
    const int cur = jt & 1;
    if (jt < qt) STAGE(cur ^ 1, jt + 1);
    const ushort* Kc = Ks[cur];
    const ushort* Vc = Vs[cur];
    const int j0 = jt * 64;
    f32x4 S[4];
#pragma unroll
    for (int n = 0; n < 4; ++n) {
      const bf16x8 k0 = *reinterpret_cast<const bf16x8*>(&Kc[(n * 16 + c) * 64 + pc0]);
      const bf16x8 k1 = *reinterpret_cast<const bf16x8*>(&Kc[(n * 16 + c) * 64 + pc1]);
      S[n] = __builtin_amdgcn_mfma_f32_16x16x32_bf16(qA[0], k0, zero4, 0, 0, 0);
      S[n] = __builtin_amdgcn_mfma_f32_16x16x32_bf16(qA[1], k1, S[n], 0, 0, 0);
    }
    const bool diag = (jt == qt);
#pragma unroll
    for (int n = 0; n < 4; ++n)
#pragma unroll
      for (int r = 0; r < 4; ++r) {
        float v = S[n][r] * SCALE;
        if (diag && (j0 + n * 16 + c) > (q0 + 4 * g + r)) v = -INFINITY;
        S[n][r] = v;
      }
    float pm[4];
    int exceed = 0;
#pragma unroll
    for (int r = 0; r < 4; ++r) {
      pm[r] = fmaxf(fmaxf(S[0][r], S[1][r]), fmaxf(S[2][r], S[3][r]));
      exceed |= (pm[r] > mrow[r] + DEFER_THR);
    }
    if (__any(exceed)) {
#pragma unroll
      for (int r = 0; r < 4; ++r) {
        float fm = pm[r];
        fm = fmaxf(fm, __shfl_xor(fm, 1, 16));
        fm = fmaxf(fm, __shfl_xor(fm, 2, 16));
        fm = fmaxf(fm, __shfl_xor(fm, 4, 16));
        fm = fmaxf(fm, __shfl_xor(fm, 8, 16));
        const float mnew = fmaxf(mrow[r], fm);
        const float corr = __expf(mrow[r] - mnew);
        lsum[r] *= corr;
#pragma unroll
        for (int t = 0; t < 4; ++t) O[t][r] *= corr;
        mrow[r] = mnew;
      }
    }
#pragma unroll
    for (int n = 0; n < 4; ++n)
#pragma unroll
      for (int r = 0; r < 4; ++r) {
        const float p = __expf(S[n][r] - mrow[r]);
        S[n][r] = p;
        lsum[r] += p;
      }
#pragma unroll
    for (int n = 0; n < 4; ++n)
#pragma unroll
      for (int r = 0; r < 4; ++r) {
        const int row = 4 * g + r;
        Pw[row * 64 + ((2 * n + (c >> 3)) ^ (row & 7)) * 8 + (c & 7)] =
            f2bf(S[n][r]);
      }
    const bf16x8 pA0 = *reinterpret_cast<const bf16x8*>(&Pw[c * 64 + pc0]);
    const bf16x8 pA1 = *reinterpret_cast<const bf16x8*>(&Pw[c * 64 + pc1]);
#pragma unroll
    for (int t = 0; t < 4; ++t) {
      const bf16x8 v0 = *reinterpret_cast<const bf16x8*>(&Vc[(t * 16 + c) * 64 + pc0]);
      const bf16x8 v1 = *reinterpret_cast<const bf16x8*>(&Vc[(t * 16 + c) * 64 + pc1]);
      O[t] = __builtin_amdgcn_mfma_f32_16x16x32_bf16(pA0, v0, O[t], 0, 0, 0);
      O[t] = __builtin_amdgcn_mfma_f32_16x16x32_bf16(pA1, v1, O[t], 0, 0, 0);
    }
    __syncthreads();
  }
  float inv[4];
#pragma unroll
  for (int r = 0; r < 4; ++r) {
    float s = lsum[r];
    s += __shfl_xor(s, 1, 16);
    s += __shfl_xor(s, 2, 16);
    s += __shfl_xor(s, 4, 16);
    s += __shfl_xor(s, 8, 16);
    inv[r] = 1.f / s;
  }
#pragma unroll
  for (int t = 0; t < 4; ++t)
#pragma unroll
    for (int r = 0; r < 4; ++r)
      attn_out[((size_t)b * L_SEQ + q0 + 4 * g + r) * C_DIM + h * DK + t * 16 + c] =
          f2bf(O[t][r] * inv[r]);
}

// ------------------------------------------------------------------- launch
extern "C" void kernel_launch(void* const* d_in, const int* in_sizes, int n_in,
                              void* d_out, int out_size, void* d_ws,
                              size_t ws_size, hipStream_t stream) {
  const float* x     = (const float*)d_in[0];
  const float* W_in  = (const float*)d_in[1];
  const float* b_in  = (const float*)d_in[2];
  const float* W_out = (const float*)d_in[3];
  const float* b_out = (const float*)d_in[4];
  float* out = (float*)d_out;

  ushort* xbf   = (ushort*)d_ws;                       // 8192x512
  ushort* WinT  = xbf + (size_t)M_ROWS * C_DIM;        // 1536x512
  ushort* WoutT = WinT + (size_t)N_QKV * C_DIM;        // 512x512
  ushort* Qo    = WoutT + (size_t)C_DIM * C_DIM;       // [BH,L,64]
  ushort* Ko    = Qo + (size_t)M_ROWS * C_DIM;         // [BH,32 tiles,4096]
  ushort* Vto   = Ko + (size_t)M_ROWS * C_DIM;         // [BH,32 tiles,4096]
  ushort* attnb = Vto + (size_t)M_ROWS * C_DIM;        // [8192,512]

  prep_fused<<<dim3(4352, 1, 1), 256, 0, stream>>>(
      x, W_in, W_out, xbf, WinT, WoutT);
  gemm_qkv<<<dim3(768, 1, 1), 256, 0, stream>>>(
      xbf, WinT, b_in, Qo, Ko, Vto, N_QKV, C_DIM, 12);
  attn_mfma<<<dim3(1024, 1, 1), 256, 0, stream>>>(Qo, Ko, Vto, attnb);
  gemm_out<<<dim3(512, 1, 1), 256, 0, stream>>>(
      attnb, WoutT, b_out, out, x, C_DIM, C_DIM, 4);
}

// Round 24
// 88.041 us; speedup vs baseline: 1.0968x; 1.0273x over previous
//
#include <hip/hip_runtime.h>
#include <hip/hip_bf16.h>
#include <math.h>
#include <cstddef>
#include <cstring>

// AttentionBlock: B=4, L=2048, C=512, H=8, Dk=64
// qkv = x @ W_in + b_in ; per head: causal-softmax(q k^T/8) @ v ; @ W_out + b_out + x

constexpr int B_SZ  = 4;
constexpr int L_SEQ = 2048;
constexpr int C_DIM = 512;
constexpr int H_N   = 8;
constexpr int DK    = 64;
constexpr int N_QKV = 1536;
constexpr int M_ROWS = B_SZ * L_SEQ; // 8192
constexpr float SCALE = 0.125f;
constexpr float DEFER_THR = 8.f;     // defer-max threshold (P <= e^8)

typedef __attribute__((ext_vector_type(4))) float f32x4;
typedef __attribute__((ext_vector_type(8))) short bf16x8;
typedef __attribute__((ext_vector_type(4))) unsigned int u32x4;

static __device__ inline ushort f2bf(float f) {
  unsigned u = __builtin_bit_cast(unsigned, f);
  u += 0x7fffu + ((u >> 16) & 1u);
  return (ushort)(u >> 16);
}

static __device__ inline unsigned pack_bf2(float a, float b) {
  const __hip_bfloat162 v = __float22bfloat162_rn(make_float2(a, b));
  unsigned u;
  __builtin_memcpy(&u, &v, 4);
  return u;
}

typedef __attribute__((address_space(1))) const unsigned int* gas1_t;
typedef __attribute__((address_space(3))) unsigned int* las3_t;
static __device__ inline void gload_lds16(const void* g, void* l) {
  __builtin_amdgcn_global_load_lds((gas1_t)g, (las3_t)l, 16, 0, 0);
}

// K/V tile format (producer-swizzled so LDS-linear staging => conflict-
// balanced ds_read_b128): per (bh, 64-j tile) an 8KB tile of [64 rows][8
// chunks of 16B]; chunk stored at (logical_chunk ^ (row & 7)). K tiles:
// row = j, elem d. V tiles: row = d, elem j.

// --------------------------------------- prep: weight transposes only
// blocks [0,192): W_in [512x1536] -> WinT [1536x512] bf16
// blocks [192,256): W_out [512x512] -> WoutT [512x512] bf16
__global__ __launch_bounds__(256) void prep_w(
    const float* __restrict__ W_in, const float* __restrict__ W_out,
    ushort* __restrict__ WinT, ushort* __restrict__ WoutT) {
  __shared__ ushort T[64][65];
  const int id = blockIdx.x;
  const float* src;
  ushort* dst;
  int R, C, c0, r0;
  if (id < 192) {
    src = W_in; dst = WinT; R = C_DIM; C = N_QKV;
    c0 = (id % 24) * 64; r0 = (id / 24) * 64;
  } else {
    const int t = id - 192;
    src = W_out; dst = WoutT; R = C_DIM; C = C_DIM;
    c0 = (t % 8) * 64; r0 = (t / 8) * 64;
  }
#pragma unroll
  for (int p = 0; p < 16; ++p) {
    const int idx = threadIdx.x + p * 256;
    const int r = idx >> 6, c = idx & 63;
    T[r][c] = f2bf(src[(size_t)(r0 + r) * C + c0 + c]);
  }
  __syncthreads();
#pragma unroll
  for (int p = 0; p < 16; ++p) {
    const int idx = threadIdx.x + p * 256;
    const int r = idx >> 6, c = idx & 63;
    dst[(size_t)(c0 + r) * R + r0 + c] = T[c][r];
  }
}

// -------------------- GEMM1: 128x128, BK=32, XCD-banded, fp32-A direct
// A = x (fp32, no pre-convert): staged fp32 into 16KB LDS, chunk-XOR-
// swizzled (phys 16B chunk p of row holds logical chunk p^(row&7); the
// global source is pre-swizzled per-lane, LDS dest linear — rule 21), and
// converted to bf16 fragments in-register via cvt_pk. With banding the
// fp32 A-band (2MB) + B panel (1.5MB) stay L2-resident per XCD, so fp32
// costs one extra HBM pass of A but deletes the 25MB convert round-trip.
__global__ __launch_bounds__(256) void gemm_qkv(
    const float* __restrict__ Af, const ushort* __restrict__ Bt,
    const float* __restrict__ bias, ushort* __restrict__ Qo,
    ushort* __restrict__ Ko, ushort* __restrict__ Vto, int N, int K, int nbx) {
  __shared__ float Alf[128 * 32];
  __shared__ ushort Bl[128 * 32];
  const int id = blockIdx.x;
  const int xcd = id & 7, i = id >> 3;
  const int bn = (i % nbx) * 128;
  const int bm = (xcd * 8 + i / nbx) * 128;
  const int tid = threadIdx.x;
  const int w = tid >> 6, l = tid & 63;
  const int cc = l & 15, gg = l >> 4;
  const int wr = w >> 1, wc = w & 1;
  f32x4 acc[4][4] = {};

  for (int k0 = 0; k0 < K; k0 += 32) {
    // A fp32: 128 rows x 32 floats = 1024 16B-chunks (4 rounds, all waves)
#pragma unroll
    for (int q = 0; q < 4; ++q) {
      const int cidx = q * 256 + tid;
      const int row = cidx >> 3, pc = cidx & 7;
      gload_lds16(Af + (size_t)(bm + row) * K + k0 + ((pc ^ (row & 7)) << 2),
                  &Alf[(q * 256 + w * 64) * 4]);
    }
    // B bf16: 128 rows x 32 = 512 16B-chunks (2 rounds)
#pragma unroll
    for (int q = 0; q < 2; ++q) {
      const int cbase = q * 256 + w * 64;
      const int c = cbase + l;
      gload_lds16(Bt + (size_t)(bn + (c >> 2)) * K + k0 + (c & 3) * 8,
                  &Bl[cbase * 8]);
    }
    __syncthreads();
    bf16x8 aF[4], bF[4];
#pragma unroll
    for (int i2 = 0; i2 < 4; ++i2) {
      const int rowA = wr * 64 + i2 * 16 + cc;   // rowA&7 == cc&7
      const float4 fa = *reinterpret_cast<const float4*>(
          &Alf[rowA * 32 + (((2 * gg) ^ (cc & 7)) << 2)]);
      const float4 fb = *reinterpret_cast<const float4*>(
          &Alf[rowA * 32 + (((2 * gg + 1) ^ (cc & 7)) << 2)]);
      u32x4 up;
      up[0] = pack_bf2(fa.x, fa.y);
      up[1] = pack_bf2(fa.z, fa.w);
      up[2] = pack_bf2(fb.x, fb.y);
      up[3] = pack_bf2(fb.z, fb.w);
      aF[i2] = __builtin_bit_cast(bf16x8, up);
    }
#pragma unroll
    for (int j = 0; j < 4; ++j)
      bF[j] = *reinterpret_cast<const bf16x8*>(
          &Bl[(wc * 64 + j * 16 + cc) * 32 + gg * 8]);
#pragma unroll
    for (int i2 = 0; i2 < 4; ++i2)
#pragma unroll
      for (int j = 0; j < 4; ++j)
        acc[i2][j] = __builtin_amdgcn_mfma_f32_16x16x32_bf16(aF[i2], bF[j],
                                                             acc[i2][j], 0, 0, 0);
    __syncthreads();
  }

#pragma unroll
  for (int j = 0; j < 4; ++j) {
    const int colbase = bn + wc * 64 + j * 16;
    const int h = colbase / 192, rem = colbase % 192;
    const int type = rem / 64, d = (rem % 64) + cc;
    const float bv = bias[colbase + cc];
#pragma unroll
    for (int i2 = 0; i2 < 4; ++i2) {
      const int rowbase = bm + wr * 64 + i2 * 16 + 4 * gg;
      const int b = rowbase >> 11, ll = rowbase & 2047;
      const size_t bh32 = (size_t)(b * H_N + h) * 32;
      if (type == 0) {
#pragma unroll
        for (int r = 0; r < 4; ++r)
          Qo[((size_t)(b * H_N + h) * L_SEQ + ll + r) * DK + d] =
              f2bf(acc[i2][j][r] + bv);
      } else if (type == 1) {
#pragma unroll
        for (int r = 0; r < 4; ++r) {
          const int jg = ll + r;
          Ko[(bh32 + (jg >> 6)) * 4096 + (jg & 63) * 64 +
             (((d >> 3) ^ (jg & 7)) << 3) + (d & 7)] =
              f2bf(acc[i2][j][r] + bv);
        }
      } else {
        ushort4 pk;
        pk.x = f2bf(acc[i2][j][0] + bv);
        pk.y = f2bf(acc[i2][j][1] + bv);
        pk.z = f2bf(acc[i2][j][2] + bv);
        pk.w = f2bf(acc[i2][j][3] + bv);
        const size_t idx = (bh32 + (ll >> 6)) * 4096 + (size_t)d * 64 +
                           ((((ll & 63) >> 3) ^ (d & 7)) << 3) + (ll & 7);
        *reinterpret_cast<ushort4*>(&Vto[idx]) = pk;
      }
    }
  }
}

// ------------------------------------- GEMM2: 64x128, BK=32, XCD-banded
// (R23 exact — 512 blocks = 2 blocks/CU.)
__global__ __launch_bounds__(256) void gemm_out(
    const ushort* __restrict__ A, const ushort* __restrict__ Bt,
    const float* __restrict__ bias, float* __restrict__ outF,
    const float* __restrict__ resid, int N, int K, int nbx) {
  __shared__ ushort Al[64 * 32];
  __shared__ ushort Bl[128 * 32];
  const int id = blockIdx.x;
  const int xcd = id & 7, i = id >> 3;
  const int bn = (i % nbx) * 128;
  const int bm = (xcd * 16 + i / nbx) * 64;
  const int tid = threadIdx.x;
  const int w = tid >> 6, l = tid & 63;
  const int cc = l & 15, gg = l >> 4;
  const int wr = w >> 1, wc = w & 1;
  f32x4 acc[2][4] = {};

  for (int k0 = 0; k0 < K; k0 += 32) {
#pragma unroll
    for (int q = 0; q < 2; ++q) {
      const int cbase = q * 256 + w * 64;
      const int c = cbase + l;
      gload_lds16(Bt + (size_t)(bn + (c >> 2)) * K + k0 + (c & 3) * 8,
                  &Bl[cbase * 8]);
    }
    {
      const int cbase = w * 64;
      const int c = cbase + l;
      gload_lds16(A + (size_t)(bm + (c >> 2)) * K + k0 + (c & 3) * 8,
                  &Al[cbase * 8]);
    }
    __syncthreads();
    bf16x8 aF[2], bF[4];
#pragma unroll
    for (int i2 = 0; i2 < 2; ++i2)
      aF[i2] = *reinterpret_cast<const bf16x8*>(
          &Al[(wr * 32 + i2 * 16 + cc) * 32 + gg * 8]);
#pragma unroll
    for (int j = 0; j < 4; ++j)
      bF[j] = *reinterpret_cast<const bf16x8*>(
          &Bl[(wc * 64 + j * 16 + cc) * 32 + gg * 8]);
#pragma unroll
    for (int i2 = 0; i2 < 2; ++i2)
#pragma unroll
      for (int j = 0; j < 4; ++j)
        acc[i2][j] = __builtin_amdgcn_mfma_f32_16x16x32_bf16(aF[i2], bF[j],
                                                             acc[i2][j], 0, 0, 0);
    __syncthreads();
  }

#pragma unroll
  for (int j = 0; j < 4; ++j) {
    const int col = bn + wc * 64 + j * 16 + cc;
    const float bv = bias[col];
#pragma unroll
    for (int i2 = 0; i2 < 2; ++i2) {
      const int rowbase = bm + wr * 32 + i2 * 16 + 4 * gg;
#pragma unroll
      for (int r = 0; r < 4; ++r) {
        const size_t off = (size_t)(rowbase + r) * N + col;
        outF[off] = acc[i2][j][r] + bv + resid[off];
      }
    }
  }
}

// ---------------------------------------------- attention core (bf16 MFMA)
// EXACT R7/R15/R19 kernel (best measured: 48.7-49.1us).
#define STAGE(buf, tile)                                                     \
  {                                                                          \
    const ushort* kg_ = KoB + (size_t)(tile) * 4096 + w * 1024 + lane * 8;   \
    const ushort* vg_ = VtB + (size_t)(tile) * 4096 + w * 1024 + lane * 8;   \
    gload_lds16(kg_, &Ks[buf][w * 1024]);                                    \
    gload_lds16(kg_ + 512, &Ks[buf][w * 1024 + 512]);                        \
    gload_lds16(vg_, &Vs[buf][w * 1024]);                                    \
    gload_lds16(vg_ + 512, &Vs[buf][w * 1024 + 512]);                        \
  }

__global__ __launch_bounds__(256, 4) void attn_mfma(
    const ushort* __restrict__ Q, const ushort* __restrict__ Ko,
    const ushort* __restrict__ Vt, ushort* __restrict__ attn_out) {
  __shared__ ushort Ks[2][4096];
  __shared__ ushort Vs[2][4096];
  __shared__ ushort Pw_s[4][1024];
  const int id = blockIdx.x;
  const int bh = (id & 7) + 8 * ((id >> 3) & 3);
  const int qt = 31 - (id >> 5);
  const int tid = threadIdx.x;
  const int w = tid >> 6, lane = tid & 63;
  const int c = lane & 15, g = lane >> 4;
  const int b = bh >> 3, h = bh & 7;
  const ushort* KoB = Ko + (size_t)bh * 32 * 4096;
  const ushort* VtB = Vt + (size_t)bh * 32 * 4096;
  const int q0 = qt * 64 + w * 16;
  ushort* Pw = Pw_s[w];
  const int pc0 = (g ^ (c & 7)) * 8;
  const int pc1 = ((g + 4) ^ (c & 7)) * 8;

  bf16x8 qA[2];
  {
    const ushort* qp = Q + ((size_t)bh * L_SEQ + q0 + c) * DK + g * 8;
    qA[0] = *reinterpret_cast<const bf16x8*>(qp);
    qA[1] = *reinterpret_cast<const bf16x8*>(qp + 32);
  }

  f32x4 O[4] = {};
  float mrow[4] = {-INFINITY, -INFINITY, -INFINITY, -INFINITY};
  float lsum[4] = {};
  const f32x4 zero4 = {0.f, 0.f, 0.f, 0.f};

  STAGE(0, 0);
  __syncthreads();

  for (int jt = 0; jt <= qt; ++jt) {
    const int cur = jt & 1;
    if (jt < qt) STAGE(cur ^ 1, jt + 1);
    const ushort* Kc = Ks[cur];
    const ushort* Vc = Vs[cur];
    const int j0 = jt * 64;
    f32x4 S[4];
#pragma unroll
    for (int n = 0; n < 4; ++n) {
      const bf16x8 k0 = *reinterpret_cast<const bf16x8*>(&Kc[(n * 16 + c) * 64 + pc0]);
      const bf16x8 k1 = *reinterpret_cast<const bf16x8*>(&Kc[(n * 16 + c) * 64 + pc1]);
      S[n] = __builtin_amdgcn_mfma_f32_16x16x32_bf16(qA[0], k0, zero4, 0, 0, 0);
      S[n] = __builtin_amdgcn_mfma_f32_16x16x32_bf16(qA[1], k1, S[n], 0, 0, 0);
    }
    const bool diag = (jt == qt);
#pragma unroll
    for (int n = 0; n < 4; ++n)
#pragma unroll
      for (int r = 0; r < 4; ++r) {
        float v = S[n][r] * SCALE;
        if (diag && (j0 + n * 16 + c) > (q0 + 4 * g + r)) v = -INFINITY;
        S[n][r] = v;
      }
    float pm[4];
    int exceed = 0;
#pragma unroll
    for (int r = 0; r < 4; ++r) {
      pm[r] = fmaxf(fmaxf(S[0][r], S[1][r]), fmaxf(S[2][r], S[3][r]));
      exceed |= (pm[r] > mrow[r] + DEFER_THR);
    }
    if (__any(exceed)) {
#pragma unroll
      for (int r = 0; r < 4; ++r) {
        float fm = pm[r];
        fm = fmaxf(fm, __shfl_xor(fm, 1, 16));
        fm = fmaxf(fm, __shfl_xor(fm, 2, 16));
        fm = fmaxf(fm, __shfl_xor(fm, 4, 16));
        fm = fmaxf(fm, __shfl_xor(fm, 8, 16));
        const float mnew = fmaxf(mrow[r], fm);
        const float corr = __expf(mrow[r] - mnew);
        lsum[r] *= corr;
#pragma unroll
        for (int t = 0; t < 4; ++t) O[t][r] *= corr;
        mrow[r] = mnew;
      }
    }
#pragma unroll
    for (int n = 0; n < 4; ++n)
#pragma unroll
      for (int r = 0; r < 4; ++r) {
        const float p = __expf(S[n][r] - mrow[r]);
        S[n][r] = p;
        lsum[r] += p;
      }
#pragma unroll
    for (int n = 0; n < 4; ++n)
#pragma unroll
      for (int r = 0; r < 4; ++r) {
        const int row = 4 * g + r;
        Pw[row * 64 + ((2 * n + (c >> 3)) ^ (row & 7)) * 8 + (c & 7)] =
            f2bf(S[n][r]);
      }
    const bf16x8 pA0 = *reinterpret_cast<const bf16x8*>(&Pw[c * 64 + pc0]);
    const bf16x8 pA1 = *reinterpret_cast<const bf16x8*>(&Pw[c * 64 + pc1]);
#pragma unroll
    for (int t = 0; t < 4; ++t) {
      const bf16x8 v0 = *reinterpret_cast<const bf16x8*>(&Vc[(t * 16 + c) * 64 + pc0]);
      const bf16x8 v1 = *reinterpret_cast<const bf16x8*>(&Vc[(t * 16 + c) * 64 + pc1]);
      O[t] = __builtin_amdgcn_mfma_f32_16x16x32_bf16(pA0, v0, O[t], 0, 0, 0);
      O[t] = __builtin_amdgcn_mfma_f32_16x16x32_bf16(pA1, v1, O[t], 0, 0, 0);
    }
    __syncthreads();
  }
  float inv[4];
#pragma unroll
  for (int r = 0; r < 4; ++r) {
    float s = lsum[r];
    s += __shfl_xor(s, 1, 16);
    s += __shfl_xor(s, 2, 16);
    s += __shfl_xor(s, 4, 16);
    s += __shfl_xor(s, 8, 16);
    inv[r] = 1.f / s;
  }
#pragma unroll
  for (int t = 0; t < 4; ++t)
#pragma unroll
    for (int r = 0; r < 4; ++r)
      attn_out[((size_t)b * L_SEQ + q0 + 4 * g + r) * C_DIM + h * DK + t * 16 + c] =
          f2bf(O[t][r] * inv[r]);
}

// ------------------------------------------------------------------- launch
extern "C" void kernel_launch(void* const* d_in, const int* in_sizes, int n_in,
                              void* d_out, int out_size, void* d_ws,
                              size_t ws_size, hipStream_t stream) {
  const float* x     = (const float*)d_in[0];
  const float* W_in  = (const float*)d_in[1];
  const float* b_in  = (const float*)d_in[2];
  const float* W_out = (const float*)d_in[3];
  const float* b_out = (const float*)d_in[4];
  float* out = (float*)d_out;

  ushort* WinT  = (ushort*)d_ws;                       // 1536x512
  ushort* WoutT = WinT + (size_t)N_QKV * C_DIM;        // 512x512
  ushort* Qo    = WoutT + (size_t)C_DIM * C_DIM;       // [BH,L,64]
  ushort* Ko    = Qo + (size_t)M_ROWS * C_DIM;         // [BH,32 tiles,4096]
  ushort* Vto   = Ko + (size_t)M_ROWS * C_DIM;         // [BH,32 tiles,4096]
  ushort* attnb = Vto + (size_t)M_ROWS * C_DIM;        // [8192,512]

  prep_w<<<dim3(256, 1, 1), 256, 0, stream>>>(W_in, W_out, WinT, WoutT);
  gemm_qkv<<<dim3(768, 1, 1), 256, 0, stream>>>(
      x, WinT, b_in, Qo, Ko, Vto, N_QKV, C_DIM, 12);
  attn_mfma<<<dim3(1024, 1, 1), 256, 0, stream>>>(Qo, Ko, Vto, attnb);
  gemm_out<<<dim3(512, 1, 1), 256, 0, stream>>>(
      attnb, WoutT, b_out, out, x, C_DIM, C_DIM, 4);
}

// Round 25
// 86.652 us; speedup vs baseline: 1.1143x; 1.0160x over previous
//
#include <hip/hip_runtime.h>
#include <hip/hip_bf16.h>
#include <math.h>
#include <cstddef>
#include <cstring>

// AttentionBlock: B=4, L=2048, C=512, H=8, Dk=64
// qkv = x @ W_in + b_in ; per head: causal-softmax(q k^T/8) @ v ; @ W_out + b_out + x

constexpr int B_SZ  = 4;
constexpr int L_SEQ = 2048;
constexpr int C_DIM = 512;
constexpr int H_N   = 8;
constexpr int DK    = 64;
constexpr int N_QKV = 1536;
constexpr int M_ROWS = B_SZ * L_SEQ; // 8192
constexpr float SCALE = 0.125f;
constexpr float DEFER_THR = 8.f;     // defer-max threshold (P <= e^8)

typedef __attribute__((ext_vector_type(4))) float f32x4;
typedef __attribute__((ext_vector_type(8))) short bf16x8;
typedef __attribute__((ext_vector_type(4))) unsigned int u32x4;

static __device__ inline ushort f2bf(float f) {
  unsigned u = __builtin_bit_cast(unsigned, f);
  u += 0x7fffu + ((u >> 16) & 1u);
  return (ushort)(u >> 16);
}

static __device__ inline unsigned pack_bf2(float a, float b) {
  const __hip_bfloat162 v = __float22bfloat162_rn(make_float2(a, b));
  unsigned u;
  __builtin_memcpy(&u, &v, 4);
  return u;
}

typedef __attribute__((address_space(1))) const unsigned int* gas1_t;
typedef __attribute__((address_space(3))) unsigned int* las3_t;
static __device__ inline void gload_lds16(const void* g, void* l) {
  __builtin_amdgcn_global_load_lds((gas1_t)g, (las3_t)l, 16, 0, 0);
}

// K/V tile format (producer-swizzled so LDS-linear staging => conflict-
// balanced ds_read_b128): per (bh, 64-j tile) an 8KB tile of [64 rows][8
// chunks of 16B]; chunk stored at (logical_chunk ^ (row & 7)). K tiles:
// row = j, elem d. V tiles: row = d, elem j.

// --------------------------------------- prep: weight transposes only
__global__ __launch_bounds__(256) void prep_w(
    const float* __restrict__ W_in, const float* __restrict__ W_out,
    ushort* __restrict__ WinT, ushort* __restrict__ WoutT) {
  __shared__ ushort T[64][65];
  const int id = blockIdx.x;
  const float* src;
  ushort* dst;
  int R, C, c0, r0;
  if (id < 192) {
    src = W_in; dst = WinT; R = C_DIM; C = N_QKV;
    c0 = (id % 24) * 64; r0 = (id / 24) * 64;
  } else {
    const int t = id - 192;
    src = W_out; dst = WoutT; R = C_DIM; C = C_DIM;
    c0 = (t % 8) * 64; r0 = (t / 8) * 64;
  }
#pragma unroll
  for (int p = 0; p < 16; ++p) {
    const int idx = threadIdx.x + p * 256;
    const int r = idx >> 6, c = idx & 63;
    T[r][c] = f2bf(src[(size_t)(r0 + r) * C + c0 + c]);
  }
  __syncthreads();
#pragma unroll
  for (int p = 0; p < 16; ++p) {
    const int idx = threadIdx.x + p * 256;
    const int r = idx >> 6, c = idx & 63;
    dst[(size_t)(c0 + r) * R + r0 + c] = T[c][r];
  }
}

// -------------------- GEMM1: 128x128, BK=32, XCD-banded, fp32-A direct
// (R24 exact — measured best.)
__global__ __launch_bounds__(256) void gemm_qkv(
    const float* __restrict__ Af, const ushort* __restrict__ Bt,
    const float* __restrict__ bias, ushort* __restrict__ Qo,
    ushort* __restrict__ Ko, ushort* __restrict__ Vto, int N, int K, int nbx) {
  __shared__ float Alf[128 * 32];
  __shared__ ushort Bl[128 * 32];
  const int id = blockIdx.x;
  const int xcd = id & 7, i = id >> 3;
  const int bn = (i % nbx) * 128;
  const int bm = (xcd * 8 + i / nbx) * 128;
  const int tid = threadIdx.x;
  const int w = tid >> 6, l = tid & 63;
  const int cc = l & 15, gg = l >> 4;
  const int wr = w >> 1, wc = w & 1;
  f32x4 acc[4][4] = {};

  for (int k0 = 0; k0 < K; k0 += 32) {
#pragma unroll
    for (int q = 0; q < 4; ++q) {
      const int cidx = q * 256 + tid;
      const int row = cidx >> 3, pc = cidx & 7;
      gload_lds16(Af + (size_t)(bm + row) * K + k0 + ((pc ^ (row & 7)) << 2),
                  &Alf[(q * 256 + w * 64) * 4]);
    }
#pragma unroll
    for (int q = 0; q < 2; ++q) {
      const int cbase = q * 256 + w * 64;
      const int c = cbase + l;
      gload_lds16(Bt + (size_t)(bn + (c >> 2)) * K + k0 + (c & 3) * 8,
                  &Bl[cbase * 8]);
    }
    __syncthreads();
    bf16x8 aF[4], bF[4];
#pragma unroll
    for (int i2 = 0; i2 < 4; ++i2) {
      const int rowA = wr * 64 + i2 * 16 + cc;   // rowA&7 == cc&7
      const float4 fa = *reinterpret_cast<const float4*>(
          &Alf[rowA * 32 + (((2 * gg) ^ (cc & 7)) << 2)]);
      const float4 fb = *reinterpret_cast<const float4*>(
          &Alf[rowA * 32 + (((2 * gg + 1) ^ (cc & 7)) << 2)]);
      u32x4 up;
      up[0] = pack_bf2(fa.x, fa.y);
      up[1] = pack_bf2(fa.z, fa.w);
      up[2] = pack_bf2(fb.x, fb.y);
      up[3] = pack_bf2(fb.z, fb.w);
      aF[i2] = __builtin_bit_cast(bf16x8, up);
    }
#pragma unroll
    for (int j = 0; j < 4; ++j)
      bF[j] = *reinterpret_cast<const bf16x8*>(
          &Bl[(wc * 64 + j * 16 + cc) * 32 + gg * 8]);
#pragma unroll
    for (int i2 = 0; i2 < 4; ++i2)
#pragma unroll
      for (int j = 0; j < 4; ++j)
        acc[i2][j] = __builtin_amdgcn_mfma_f32_16x16x32_bf16(aF[i2], bF[j],
                                                             acc[i2][j], 0, 0, 0);
    __syncthreads();
  }

#pragma unroll
  for (int j = 0; j < 4; ++j) {
    const int colbase = bn + wc * 64 + j * 16;
    const int h = colbase / 192, rem = colbase % 192;
    const int type = rem / 64, d = (rem % 64) + cc;
    const float bv = bias[colbase + cc];
#pragma unroll
    for (int i2 = 0; i2 < 4; ++i2) {
      const int rowbase = bm + wr * 64 + i2 * 16 + 4 * gg;
      const int b = rowbase >> 11, ll = rowbase & 2047;
      const size_t bh32 = (size_t)(b * H_N + h) * 32;
      if (type == 0) {
#pragma unroll
        for (int r = 0; r < 4; ++r)
          Qo[((size_t)(b * H_N + h) * L_SEQ + ll + r) * DK + d] =
              f2bf(acc[i2][j][r] + bv);
      } else if (type == 1) {
#pragma unroll
        for (int r = 0; r < 4; ++r) {
          const int jg = ll + r;
          Ko[(bh32 + (jg >> 6)) * 4096 + (jg & 63) * 64 +
             (((d >> 3) ^ (jg & 7)) << 3) + (d & 7)] =
              f2bf(acc[i2][j][r] + bv);
        }
      } else {
        ushort4 pk;
        pk.x = f2bf(acc[i2][j][0] + bv);
        pk.y = f2bf(acc[i2][j][1] + bv);
        pk.z = f2bf(acc[i2][j][2] + bv);
        pk.w = f2bf(acc[i2][j][3] + bv);
        const size_t idx = (bh32 + (ll >> 6)) * 4096 + (size_t)d * 64 +
                           ((((ll & 63) >> 3) ^ (d & 7)) << 3) + (ll & 7);
        *reinterpret_cast<ushort4*>(&Vto[idx]) = pk;
      }
    }
  }
}

// -------------------------------- GEMM2: 64x64, BK=32, XCD-banded, 4/CU
// 1024 blocks (vs 512 at 64x128): same total staging volume, double the
// co-residency -> staging latency overlapped. Wave = 32x32 quadrant
// (2x2 frags). B panel 0.5MB L2-resident per XCD.
__global__ __launch_bounds__(256) void gemm_out(
    const ushort* __restrict__ A, const ushort* __restrict__ Bt,
    const float* __restrict__ bias, float* __restrict__ outF,
    const float* __restrict__ resid, int N, int K, int nbx) {
  __shared__ ushort Al[64 * 32];
  __shared__ ushort Bl[64 * 32];
  const int id = blockIdx.x;
  const int xcd = id & 7, i = id >> 3;
  const int bn = (i % nbx) * 64;
  const int bm = (xcd * 16 + i / nbx) * 64;
  const int tid = threadIdx.x;
  const int w = tid >> 6, l = tid & 63;
  const int cc = l & 15, gg = l >> 4;
  const int wr = w >> 1, wc = w & 1;          // wave quadrant 32x32
  f32x4 acc[2][2] = {};

  for (int k0 = 0; k0 < K; k0 += 32) {
    // A: 64x32 = 256 chunks (1 round); B: 64x32 = 256 chunks (1 round)
    {
      const int c = w * 64 + l;
      gload_lds16(A + (size_t)(bm + (c >> 2)) * K + k0 + (c & 3) * 8,
                  &Al[(w * 64) * 8]);
    }
    {
      const int c = w * 64 + l;
      gload_lds16(Bt + (size_t)(bn + (c >> 2)) * K + k0 + (c & 3) * 8,
                  &Bl[(w * 64) * 8]);
    }
    __syncthreads();
    bf16x8 aF[2], bF[2];
#pragma unroll
    for (int i2 = 0; i2 < 2; ++i2)
      aF[i2] = *reinterpret_cast<const bf16x8*>(
          &Al[(wr * 32 + i2 * 16 + cc) * 32 + gg * 8]);
#pragma unroll
    for (int j = 0; j < 2; ++j)
      bF[j] = *reinterpret_cast<const bf16x8*>(
          &Bl[(wc * 32 + j * 16 + cc) * 32 + gg * 8]);
#pragma unroll
    for (int i2 = 0; i2 < 2; ++i2)
#pragma unroll
      for (int j = 0; j < 2; ++j)
        acc[i2][j] = __builtin_amdgcn_mfma_f32_16x16x32_bf16(aF[i2], bF[j],
                                                             acc[i2][j], 0, 0, 0);
    __syncthreads();
  }

#pragma unroll
  for (int j = 0; j < 2; ++j) {
    const int col = bn + wc * 32 + j * 16 + cc;
    const float bv = bias[col];
#pragma unroll
    for (int i2 = 0; i2 < 2; ++i2) {
      const int rowbase = bm + wr * 32 + i2 * 16 + 4 * gg;
#pragma unroll
      for (int r = 0; r < 4; ++r) {
        const size_t off = (size_t)(rowbase + r) * N + col;
        outF[off] = acc[i2][j][r] + bv + resid[off];
      }
    }
  }
}

// ---------------------------------------------- attention core (bf16 MFMA)
// EXACT R7/R15/R19 kernel (best measured: 48.7-49.1us).
#define STAGE(buf, tile)                                                     \
  {                                                                          \
    const ushort* kg_ = KoB + (size_t)(tile) * 4096 + w * 1024 + lane * 8;   \
    const ushort* vg_ = VtB + (size_t)(tile) * 4096 + w * 1024 + lane * 8;   \
    gload_lds16(kg_, &Ks[buf][w * 1024]);                                    \
    gload_lds16(kg_ + 512, &Ks[buf][w * 1024 + 512]);                        \
    gload_lds16(vg_, &Vs[buf][w * 1024]);                                    \
    gload_lds16(vg_ + 512, &Vs[buf][w * 1024 + 512]);                        \
  }

__global__ __launch_bounds__(256, 4) void attn_mfma(
    const ushort* __restrict__ Q, const ushort* __restrict__ Ko,
    const ushort* __restrict__ Vt, ushort* __restrict__ attn_out) {
  __shared__ ushort Ks[2][4096];
  __shared__ ushort Vs[2][4096];
  __shared__ ushort Pw_s[4][1024];
  const int id = blockIdx.x;
  const int bh = (id & 7) + 8 * ((id >> 3) & 3);
  const int qt = 31 - (id >> 5);
  const int tid = threadIdx.x;
  const int w = tid >> 6, lane = tid & 63;
  const int c = lane & 15, g = lane >> 4;
  const int b = bh >> 3, h = bh & 7;
  const ushort* KoB = Ko + (size_t)bh * 32 * 4096;
  const ushort* VtB = Vt + (size_t)bh * 32 * 4096;
  const int q0 = qt * 64 + w * 16;
  ushort* Pw = Pw_s[w];
  const int pc0 = (g ^ (c & 7)) * 8;
  const int pc1 = ((g + 4) ^ (c & 7)) * 8;

  bf16x8 qA[2];
  {
    const ushort* qp = Q + ((size_t)bh * L_SEQ + q0 + c) * DK + g * 8;
    qA[0] = *reinterpret_cast<const bf16x8*>(qp);
    qA[1] = *reinterpret_cast<const bf16x8*>(qp + 32);
  }

  f32x4 O[4] = {};
  float mrow[4] = {-INFINITY, -INFINITY, -INFINITY, -INFINITY};
  float lsum[4] = {};
  const f32x4 zero4 = {0.f, 0.f, 0.f, 0.f};

  STAGE(0, 0);
  __syncthreads();

  for (int jt = 0; jt <= qt; ++jt) {
    const int cur = jt & 1;
    if (jt < qt) STAGE(cur ^ 1, jt + 1);
    const ushort* Kc = Ks[cur];
    const ushort* Vc = Vs[cur];
    const int j0 = jt * 64;
    f32x4 S[4];
#pragma unroll
    for (int n = 0; n < 4; ++n) {
      const bf16x8 k0 = *reinterpret_cast<const bf16x8*>(&Kc[(n * 16 + c) * 64 + pc0]);
      const bf16x8 k1 = *reinterpret_cast<const bf16x8*>(&Kc[(n * 16 + c) * 64 + pc1]);
      S[n] = __builtin_amdgcn_mfma_f32_16x16x32_bf16(qA[0], k0, zero4, 0, 0, 0);
      S[n] = __builtin_amdgcn_mfma_f32_16x16x32_bf16(qA[1], k1, S[n], 0, 0, 0);
    }
    const bool diag = (jt == qt);
#pragma unroll
    for (int n = 0; n < 4; ++n)
#pragma unroll
      for (int r = 0; r < 4; ++r) {
        float v = S[n][r] * SCALE;
        if (diag && (j0 + n * 16 + c) > (q0 + 4 * g + r)) v = -INFINITY;
        S[n][r] = v;
      }
    float pm[4];
    int exceed = 0;
#pragma unroll
    for (int r = 0; r < 4; ++r) {
      pm[r] = fmaxf(fmaxf(S[0][r], S[1][r]), fmaxf(S[2][r], S[3][r]));
      exceed |= (pm[r] > mrow[r] + DEFER_THR);
    }
    if (__any(exceed)) {
#pragma unroll
      for (int r = 0; r < 4; ++r) {
        float fm = pm[r];
        fm = fmaxf(fm, __shfl_xor(fm, 1, 16));
        fm = fmaxf(fm, __shfl_xor(fm, 2, 16));
        fm = fmaxf(fm, __shfl_xor(fm, 4, 16));
        fm = fmaxf(fm, __shfl_xor(fm, 8, 16));
        const float mnew = fmaxf(mrow[r], fm);
        const float corr = __expf(mrow[r] - mnew);
        lsum[r] *= corr;
#pragma unroll
        for (int t = 0; t < 4; ++t) O[t][r] *= corr;
        mrow[r] = mnew;
      }
    }
#pragma unroll
    for (int n = 0; n < 4; ++n)
#pragma unroll
      for (int r = 0; r < 4; ++r) {
        const float p = __expf(S[n][r] - mrow[r]);
        S[n][r] = p;
        lsum[r] += p;
      }
#pragma unroll
    for (int n = 0; n < 4; ++n)
#pragma unroll
      for (int r = 0; r < 4; ++r) {
        const int row = 4 * g + r;
        Pw[row * 64 + ((2 * n + (c >> 3)) ^ (row & 7)) * 8 + (c & 7)] =
            f2bf(S[n][r]);
      }
    const bf16x8 pA0 = *reinterpret_cast<const bf16x8*>(&Pw[c * 64 + pc0]);
    const bf16x8 pA1 = *reinterpret_cast<const bf16x8*>(&Pw[c * 64 + pc1]);
#pragma unroll
    for (int t = 0; t < 4; ++t) {
      const bf16x8 v0 = *reinterpret_cast<const bf16x8*>(&Vc[(t * 16 + c) * 64 + pc0]);
      const bf16x8 v1 = *reinterpret_cast<const bf16x8*>(&Vc[(t * 16 + c) * 64 + pc1]);
      O[t] = __builtin_amdgcn_mfma_f32_16x16x32_bf16(pA0, v0, O[t], 0, 0, 0);
      O[t] = __builtin_amdgcn_mfma_f32_16x16x32_bf16(pA1, v1, O[t], 0, 0, 0);
    }
    __syncthreads();
  }
  float inv[4];
#pragma unroll
  for (int r = 0; r < 4; ++r) {
    float s = lsum[r];
    s += __shfl_xor(s, 1, 16);
    s += __shfl_xor(s, 2, 16);
    s += __shfl_xor(s, 4, 16);
    s += __shfl_xor(s, 8, 16);
    inv[r] = 1.f / s;
  }
#pragma unroll
  for (int t = 0; t < 4; ++t)
#pragma unroll
    for (int r = 0; r < 4; ++r)
      attn_out[((size_t)b * L_SEQ + q0 + 4 * g + r) * C_DIM + h * DK + t * 16 + c] =
          f2bf(O[t][r] * inv[r]);
}

// ------------------------------------------------------------------- launch
extern "C" void kernel_launch(void* const* d_in, const int* in_sizes, int n_in,
                              void* d_out, int out_size, void* d_ws,
                              size_t ws_size, hipStream_t stream) {
  const float* x     = (const float*)d_in[0];
  const float* W_in  = (const float*)d_in[1];
  const float* b_in  = (const float*)d_in[2];
  const float* W_out = (const float*)d_in[3];
  const float* b_out = (const float*)d_in[4];
  float* out = (float*)d_out;

  ushort* WinT  = (ushort*)d_ws;                       // 1536x512
  ushort* WoutT = WinT + (size_t)N_QKV * C_DIM;        // 512x512
  ushort* Qo    = WoutT + (size_t)C_DIM * C_DIM;       // [BH,L,64]
  ushort* Ko    = Qo + (size_t)M_ROWS * C_DIM;         // [BH,32 tiles,4096]
  ushort* Vto   = Ko + (size_t)M_ROWS * C_DIM;         // [BH,32 tiles,4096]
  ushort* attnb = Vto + (size_t)M_ROWS * C_DIM;        // [8192,512]

  prep_w<<<dim3(256, 1, 1), 256, 0, stream>>>(W_in, W_out, WinT, WoutT);
  gemm_qkv<<<dim3(768, 1, 1), 256, 0, stream>>>(
      x, WinT, b_in, Qo, Ko, Vto, N_QKV, C_DIM, 12);
  attn_mfma<<<dim3(1024, 1, 1), 256, 0, stream>>>(Qo, Ko, Vto, attnb);
  gemm_out<<<dim3(1024, 1, 1), 256, 0, stream>>>(
      attnb, WoutT, b_out, out, x, C_DIM, C_DIM, 8);
}